// Round 6
// baseline (534.578 us; speedup 1.0000x reference)
//
#include <hip/hip_runtime.h>

typedef __attribute__((ext_vector_type(8))) __bf16 bf16x8;
typedef __attribute__((ext_vector_type(4))) float f32x4;

#define IMG 112
#define SHF 3

__device__ __forceinline__ ushort f2bf(float f) {
  return __builtin_bit_cast(unsigned short, static_cast<__bf16>(f));
}
__device__ __forceinline__ uint pk2(float lo, float hi) {
  return (uint)f2bf(lo) | ((uint)f2bf(hi) << 16);
}
__device__ __forceinline__ int d7(int n) { return (n * 9363) >> 16; }  // n/7 for n<=63

__device__ __forceinline__ bf16x8 mk8(const float4 a, const float4 b) {
  union { uint4 u; bf16x8 v; } r;
  r.u = uint4{ pk2(a.x, a.y), pk2(a.z, a.w), pk2(b.x, b.y), pk2(b.z, b.w) };
  return r.v;
}

// ---------------- prep: bf16 weights (+q scale*log2e fold), biases, rpb+mask table ----------------
// wRM[cls][h][64 qt][64 kt] = log2e * (rpb + shift/pad masks); exp() done as exp2().
__global__ void prep_kernel(const float* __restrict__ Wq, const float* __restrict__ Wk,
                            const float* __restrict__ Wv, const float* __restrict__ Wp,
                            const float* __restrict__ bq, const float* __restrict__ bk,
                            const float* __restrict__ bv, const float* __restrict__ bp,
                            const float* __restrict__ tbl,
                            ushort* __restrict__ wW, float* __restrict__ wB,
                            float* __restrict__ wRM) {
  int t = blockIdx.x * 256 + threadIdx.x;
  const float LOG2E = 1.4426950408889634f;
  const float SC = 0.17677669529663687f * LOG2E;  // 32^-0.5 * log2(e)
  if (t < 65536) {
    int m = t >> 14, e = t & 16383;
    const float* W = (m == 0) ? Wq : (m == 1) ? Wk : (m == 2) ? Wv : Wp;
    float v = W[e];
    if (m == 0) v *= SC;
    wW[t] = f2bf(v);
  } else if (t < 66048) {
    int t2 = t - 65536;
    int m = t2 >> 7, e = t2 & 127;
    const float* B = (m == 0) ? bq : (m == 1) ? bk : (m == 2) ? bv : bp;
    float v = B[e];
    if (m == 0) v *= SC;
    wB[t2] = v;
  } else if (t < 131584) {
    int t3 = t - 66048;  // [0, 65536)
    int cls = t3 >> 14;
    int r = t3 & 16383;
    int h = r >> 12;
    int rr = r & 4095;
    int qt = rr >> 6, kt = rr & 63;
    float v;
    if (qt >= 49) v = 0.0f;
    else if (kt >= 49) v = -1e30f;
    else {
      int rq = qt / 7, cq = qt % 7, rk = kt / 7, ck = kt % 7;
      v = tbl[((rq - rk + 6) * 13 + (cq - ck + 6)) * 4 + h];
      int eH = (cls >> 1) & 1, eW = cls & 1;
      int ridq = (eH ? (rq < 4 ? 3 : 6) : 0) + (eW ? (cq < 4 ? 1 : 2) : 0);
      int ridk = (eH ? (rk < 4 ? 3 : 6) : 0) + (eW ? (ck < 4 ? 1 : 2) : 0);
      if (ridq != ridk) v -= 100.0f;
    }
    wRM[t3] = v * LOG2E;
  }
}

// LDS layout (ushort units), 25096 ushorts = 50.2 KB:
//  R0 [0, 9216)      : p_s[2][64][72] (attn)  |  o_s[49][136] (proj in)
//  KS [9216, 15880)  : k_s[49][136]   ([token][channel])
//  VT [15880, 25096) : vT[128][72]    ([channel][token])
#define KS 9216
#define VT 15880

__global__ __launch_bounds__(512, 4) void swin_kernel(
    const float* __restrict__ X, const ushort* __restrict__ wW,
    const float* __restrict__ wB, const float* __restrict__ wRM,
    float* __restrict__ out) {
  __shared__ ushort lds[25096];
  const int tid = threadIdx.x;
  const int wv = tid >> 6;  // 0..7
  const int lane = tid & 63;
  const int lr = lane & 15;
  const int kg = lane >> 4;

  const int blk = blockIdx.x;
  const int b = blk >> 8;
  const int wid = blk & 255;
  const int wi = wid >> 4, wj = wid & 15;
  const size_t gBase = (size_t)b * (IMG * IMG * 128);

  const int wc = wv & 3, wt = wv >> 2;
  const int c0 = wc * 32, t0 = wt * 32;
  const int hloc = wv >> 2, mq = wv & 3;  // attn identity
  const int qt = mq * 16 + lr;
  const int qtc = qt > 48 ? 48 : qt;

  // rolled-pixel pointer for a token
  auto pixptr = [&](int tok) -> const float* {
    int r = d7(tok), c = tok - r * 7;
    int gh = wi * 7 + r + SHF; if (gh >= IMG) gh -= IMG;
    int gw = wj * 7 + c + SHF; if (gw >= IMG) gw -= IMG;
    return X + gBase + ((size_t)gh * IMG + gw) * 128;
  };

  // ---------------- x fragments straight from global (f32 -> bf16 in regs) ----------------
  // xf[kk][nt]: tokens t0+nt*16+lr, channels kk*32+kg*8..+8. Serves as B-op (col=tok)
  // for the K-proj AND as A-op (row=tok) for the V-proj (identical lane layouts).
  bf16x8 xf[4][2], xq[4];
  {
    int tokA = t0 + lr;      if (tokA > 48) tokA = 48;
    int tokB = t0 + 16 + lr; if (tokB > 48) tokB = 48;
    const float* pA = pixptr(tokA) + kg * 8;
    const float* pB = pixptr(tokB) + kg * 8;
    const float* pQ = pixptr(qtc) + kg * 8;
#pragma unroll
    for (int kk = 0; kk < 4; ++kk) {
      float4 a0 = *reinterpret_cast<const float4*>(pA + kk * 32);
      float4 a1 = *reinterpret_cast<const float4*>(pA + kk * 32 + 4);
      float4 b0 = *reinterpret_cast<const float4*>(pB + kk * 32);
      float4 b1 = *reinterpret_cast<const float4*>(pB + kk * 32 + 4);
      float4 q0 = *reinterpret_cast<const float4*>(pQ + kk * 32);
      float4 q1 = *reinterpret_cast<const float4*>(pQ + kk * 32 + 4);
      xf[kk][0] = mk8(a0, a1);
      xf[kk][1] = mk8(b0, b1);
      xq[kk] = mk8(q0, q1);
    }
  }

  // ---------------- Fused K+V projections ----------------
  {
    f32x4 accK[2][2] = {}, accV[2][2] = {};
    const ushort* WK = wW + 16384;
    const ushort* WV = wW + 2 * 16384;
#pragma unroll
    for (int kk = 0; kk < 4; ++kk) {
      bf16x8 awK[2], bwV[2];
#pragma unroll
      for (int mt = 0; mt < 2; ++mt) {
        awK[mt] = *reinterpret_cast<const bf16x8*>(&WK[(c0 + mt * 16 + lr) * 128 + kk * 32 + kg * 8]);
        bwV[mt] = *reinterpret_cast<const bf16x8*>(&WV[(c0 + mt * 16 + lr) * 128 + kk * 32 + kg * 8]);
      }
#pragma unroll
      for (int mt = 0; mt < 2; ++mt)
#pragma unroll
        for (int nt = 0; nt < 2; ++nt) {
          accK[mt][nt] = __builtin_amdgcn_mfma_f32_16x16x32_bf16(awK[mt], xf[kk][nt], accK[mt][nt], 0, 0, 0);
          accV[mt][nt] = __builtin_amdgcn_mfma_f32_16x16x32_bf16(xf[kk][mt], bwV[nt], accV[mt][nt], 0, 0, 0);
        }
    }
    // K: D[ch][tok] -> k_s[tok][ch]
#pragma unroll
    for (int mt = 0; mt < 2; ++mt) {
      float4 b4 = *reinterpret_cast<const float4*>(&wB[128 + c0 + mt * 16 + kg * 4]);
#pragma unroll
      for (int nt = 0; nt < 2; ++nt) {
        int tok = t0 + nt * 16 + lr;
        if (tok < 49) {
          ushort4 h4 = { f2bf(accK[mt][nt][0] + b4.x), f2bf(accK[mt][nt][1] + b4.y),
                         f2bf(accK[mt][nt][2] + b4.z), f2bf(accK[mt][nt][3] + b4.w) };
          *reinterpret_cast<ushort4*>(&lds[KS + tok * 136 + c0 + mt * 16 + kg * 4]) = h4;
        }
      }
    }
    // V: D[tok][ch] -> vT[ch][tok]
#pragma unroll
    for (int nt = 0; nt < 2; ++nt) {
      float bias = wB[256 + c0 + nt * 16 + lr];
#pragma unroll
      for (int mt = 0; mt < 2; ++mt) {
        ushort4 h4 = { f2bf(accV[mt][nt][0] + bias), f2bf(accV[mt][nt][1] + bias),
                       f2bf(accV[mt][nt][2] + bias), f2bf(accV[mt][nt][3] + bias) };
        *reinterpret_cast<ushort4*>(&lds[VT + (c0 + nt * 16 + lr) * 72 + t0 + mt * 16 + kg * 4]) = h4;
      }
    }
  }

  // ---------------- this wave's own Q -> registers (B-fragment via bpermute) ----------------
  uint4 qfrag[2];
  {
    const int aA = ((kg & 1) * 32 + lr) * 4;
    const int aB = aA + 64;
#pragma unroll
    for (int hh = 0; hh < 2; ++hh) {
      const int h = hh * 2 + hloc;
      f32x4 a0 = {}, a1 = {};
#pragma unroll
      for (int kk = 0; kk < 4; ++kk) {
        bf16x8 aw0 = *reinterpret_cast<const bf16x8*>(&wW[(h * 32 + lr) * 128 + kk * 32 + kg * 8]);
        bf16x8 aw1 = *reinterpret_cast<const bf16x8*>(&wW[(h * 32 + 16 + lr) * 128 + kk * 32 + kg * 8]);
        a0 = __builtin_amdgcn_mfma_f32_16x16x32_bf16(aw0, xq[kk], a0, 0, 0, 0);
        a1 = __builtin_amdgcn_mfma_f32_16x16x32_bf16(aw1, xq[kk], a1, 0, 0, 0);
      }
      float4 b0 = *reinterpret_cast<const float4*>(&wB[h * 32 + kg * 4]);
      float4 b1 = *reinterpret_cast<const float4*>(&wB[h * 32 + 16 + kg * 4]);
      uint pk00 = pk2(a0[0] + b0.x, a0[1] + b0.y);
      uint pk01 = pk2(a0[2] + b0.z, a0[3] + b0.w);
      uint pk10 = pk2(a1[0] + b1.x, a1[1] + b1.y);
      uint pk11 = pk2(a1[2] + b1.z, a1[3] + b1.w);
      uint b00 = (uint)__builtin_amdgcn_ds_bpermute(aA, (int)pk00);
      uint b10 = (uint)__builtin_amdgcn_ds_bpermute(aA, (int)pk10);
      uint b01 = (uint)__builtin_amdgcn_ds_bpermute(aA, (int)pk01);
      uint b11 = (uint)__builtin_amdgcn_ds_bpermute(aA, (int)pk11);
      uint b02 = (uint)__builtin_amdgcn_ds_bpermute(aB, (int)pk00);
      uint b12 = (uint)__builtin_amdgcn_ds_bpermute(aB, (int)pk10);
      uint b03 = (uint)__builtin_amdgcn_ds_bpermute(aB, (int)pk01);
      uint b13 = (uint)__builtin_amdgcn_ds_bpermute(aB, (int)pk11);
      bool lo = (kg < 2);
      qfrag[hh] = uint4{ lo ? b00 : b10, lo ? b01 : b11, lo ? b02 : b12, lo ? b03 : b13 };
    }
  }
  __syncthreads();  // barrier 1: k_s / vT visible

  // ---------------- Attention: both heads' S up front; exp2; deferred norm ----------------
  const int cls = ((wi == 15) ? 2 : 0) + ((wj == 15) ? 1 : 0);
  f32x4 oaccA[2] = {}, oaccB[2] = {};
  float invA, invB;
  {
    __builtin_amdgcn_s_setprio(1);
    float4 rA[4], rB[4];
    const float* rp0 = wRM + (((size_t)cls * 4 + hloc) * 64 + qt) * 64;
    const float* rp1 = wRM + (((size_t)cls * 4 + 2 + hloc) * 64 + qt) * 64;
#pragma unroll
    for (int at = 0; at < 4; ++at) {
      rA[at] = *reinterpret_cast<const float4*>(&rp0[at * 16 + kg * 4]);
      rB[at] = *reinterpret_cast<const float4*>(&rp1[at * 16 + kg * 4]);
    }
    union { uint4 u; bf16x8 v; } qa, qb;
    qa.u = qfrag[0]; qb.u = qfrag[1];
    f32x4 sA[4] = {}, sB[4] = {};
#pragma unroll
    for (int at = 0; at < 4; ++at) {
      int kt = at * 16 + lr; if (kt > 48) kt = 48;
      bf16x8 akA = *reinterpret_cast<const bf16x8*>(&lds[KS + kt * 136 + hloc * 32 + kg * 8]);
      bf16x8 akB = *reinterpret_cast<const bf16x8*>(&lds[KS + kt * 136 + (2 + hloc) * 32 + kg * 8]);
      sA[at] = __builtin_amdgcn_mfma_f32_16x16x32_bf16(akA, qa.v, sA[at], 0, 0, 0);
      sB[at] = __builtin_amdgcn_mfma_f32_16x16x32_bf16(akB, qb.v, sB[at], 0, 0, 0);
    }
    const int pb = hloc * 4608 + qt * 72;
    float sumA = 0.0f, sumB = 0.0f;
    // ---- head A finish ----
#pragma unroll
    for (int at = 0; at < 4; ++at) {
#pragma unroll
      for (int i = 0; i < 4; ++i) {
        float e = exp2f(fminf(sA[at][i] + rA[at][i], 80.0f));
        sA[at][i] = e; sumA += e;
      }
    }
#pragma unroll
    for (int at = 0; at < 4; ++at) {
      ushort4 p4 = { f2bf(sA[at][0]), f2bf(sA[at][1]), f2bf(sA[at][2]), f2bf(sA[at][3]) };
      *reinterpret_cast<ushort4*>(&lds[pb + at * 16 + kg * 4]) = p4;
    }
#pragma unroll
    for (int kk = 0; kk < 2; ++kk) {
      bf16x8 bp = *reinterpret_cast<const bf16x8*>(&lds[pb + kk * 32 + kg * 8]);
#pragma unroll
      for (int mt = 0; mt < 2; ++mt) {
        bf16x8 av = *reinterpret_cast<const bf16x8*>(&lds[VT + (hloc * 32 + mt * 16 + lr) * 72 + kk * 32 + kg * 8]);
        oaccA[mt] = __builtin_amdgcn_mfma_f32_16x16x32_bf16(av, bp, oaccA[mt], 0, 0, 0);
      }
    }
    // ---- head B finish (reuses pb rows; same-wave DS ordering guarantees bp read saw A) ----
#pragma unroll
    for (int at = 0; at < 4; ++at) {
#pragma unroll
      for (int i = 0; i < 4; ++i) {
        float e = exp2f(fminf(sB[at][i] + rB[at][i], 80.0f));
        sB[at][i] = e; sumB += e;
      }
    }
#pragma unroll
    for (int at = 0; at < 4; ++at) {
      ushort4 p4 = { f2bf(sB[at][0]), f2bf(sB[at][1]), f2bf(sB[at][2]), f2bf(sB[at][3]) };
      *reinterpret_cast<ushort4*>(&lds[pb + at * 16 + kg * 4]) = p4;
    }
#pragma unroll
    for (int kk = 0; kk < 2; ++kk) {
      bf16x8 bp = *reinterpret_cast<const bf16x8*>(&lds[pb + kk * 32 + kg * 8]);
#pragma unroll
      for (int mt = 0; mt < 2; ++mt) {
        bf16x8 av = *reinterpret_cast<const bf16x8*>(&lds[VT + ((2 + hloc) * 32 + mt * 16 + lr) * 72 + kk * 32 + kg * 8]);
        oaccB[mt] = __builtin_amdgcn_mfma_f32_16x16x32_bf16(av, bp, oaccB[mt], 0, 0, 0);
      }
    }
    __builtin_amdgcn_s_setprio(0);
    // deferred row-sum reduction (off the MFMA chain)
    sumA += __shfl_xor(sumA, 16); sumA += __shfl_xor(sumA, 32);
    sumB += __shfl_xor(sumB, 16); sumB += __shfl_xor(sumB, 32);
    invA = 1.0f / sumA; invB = 1.0f / sumB;
  }
  __syncthreads();  // barrier 2: all p_s reads done before o_s overwrites R0

  // ---------------- O (scaled) -> o_s[tok][ch] ----------------
  if (qt < 49) {
#pragma unroll
    for (int mt = 0; mt < 2; ++mt) {
      ushort4 hA = { f2bf(oaccA[mt][0] * invA), f2bf(oaccA[mt][1] * invA),
                     f2bf(oaccA[mt][2] * invA), f2bf(oaccA[mt][3] * invA) };
      *reinterpret_cast<ushort4*>(&lds[qt * 136 + hloc * 32 + mt * 16 + kg * 4]) = hA;
      ushort4 hB = { f2bf(oaccB[mt][0] * invB), f2bf(oaccB[mt][1] * invB),
                     f2bf(oaccB[mt][2] * invB), f2bf(oaccB[mt][3] * invB) };
      *reinterpret_cast<ushort4*>(&lds[qt * 136 + (2 + hloc) * 32 + mt * 16 + kg * 4]) = hB;
    }
  }
  __syncthreads();  // barrier 3

  // ---------------- output projection (swapped) + float4 scatter ----------------
  {
    const ushort* W = wW + 3 * 16384;
    f32x4 acc[2][2] = {};
#pragma unroll
    for (int kk = 0; kk < 4; ++kk) {
      bf16x8 aw[2], bo[2];
#pragma unroll
      for (int mt = 0; mt < 2; ++mt)
        aw[mt] = *reinterpret_cast<const bf16x8*>(&W[(c0 + mt * 16 + lr) * 128 + kk * 32 + kg * 8]);
#pragma unroll
      for (int nt = 0; nt < 2; ++nt) {
        int tok = t0 + nt * 16 + lr; if (tok > 48) tok = 48;
        bo[nt] = *reinterpret_cast<const bf16x8*>(&lds[tok * 136 + kk * 32 + kg * 8]);
      }
#pragma unroll
      for (int mt = 0; mt < 2; ++mt)
#pragma unroll
        for (int nt = 0; nt < 2; ++nt)
          acc[mt][nt] = __builtin_amdgcn_mfma_f32_16x16x32_bf16(aw[mt], bo[nt], acc[mt][nt], 0, 0, 0);
    }
#pragma unroll
    for (int mt = 0; mt < 2; ++mt) {
      float4 b4 = *reinterpret_cast<const float4*>(&wB[384 + c0 + mt * 16 + kg * 4]);
#pragma unroll
      for (int nt = 0; nt < 2; ++nt) {
        int tok = t0 + nt * 16 + lr;
        if (tok < 49) {
          int r = d7(tok), c = tok - r * 7;
          int gh = wi * 7 + r + SHF; if (gh >= IMG) gh -= IMG;
          int gw = wj * 7 + c + SHF; if (gw >= IMG) gw -= IMG;
          float4 o4 = { acc[mt][nt][0] + b4.x, acc[mt][nt][1] + b4.y,
                        acc[mt][nt][2] + b4.z, acc[mt][nt][3] + b4.w };
          *reinterpret_cast<float4*>(out + gBase + ((size_t)gh * IMG + gw) * 128 + c0 + mt * 16 + kg * 4) = o4;
        }
      }
    }
  }
}

extern "C" void kernel_launch(void* const* d_in, const int* in_sizes, int n_in,
                              void* d_out, int out_size, void* d_ws, size_t ws_size,
                              hipStream_t stream) {
  const float* X = (const float*)d_in[0];
  const float* Wq = (const float*)d_in[3];
  const float* Wk = (const float*)d_in[4];
  const float* Wv = (const float*)d_in[5];
  const float* Wp = (const float*)d_in[6];
  const float* bq = (const float*)d_in[7];
  const float* bk = (const float*)d_in[8];
  const float* bv = (const float*)d_in[9];
  const float* bp = (const float*)d_in[10];
  const float* tbl = (const float*)d_in[11];

  ushort* wW = (ushort*)d_ws;                             // 4 x [128][128] bf16 = 131072 B
  float* wB = (float*)((char*)d_ws + 131072);             // 4 x [128] f32   = 2048 B
  float* wRM = (float*)((char*)d_ws + 131072 + 2048);     // [4][4][64][64] f32 = 262144 B

  prep_kernel<<<dim3(514), dim3(256), 0, stream>>>(Wq, Wk, Wv, Wp, bq, bk, bv, bp, tbl, wW, wB, wRM);
  swin_kernel<<<dim3(8192), dim3(512), 0, stream>>>(X, wW, wB, wRM, (float*)d_out);
}

// Round 7
// 373.032 us; speedup vs baseline: 1.4331x; 1.4331x over previous
//
#include <hip/hip_runtime.h>

typedef __attribute__((ext_vector_type(8))) __bf16 bf16x8;
typedef __attribute__((ext_vector_type(4))) float f32x4;

#define IMG 112
#define SHF 3

__device__ __forceinline__ ushort f2bf(float f) {
  return __builtin_bit_cast(unsigned short, static_cast<__bf16>(f));
}
__device__ __forceinline__ int d7(int n) { return (n * 9363) >> 16; }  // n/7 for n<=63

// ---------------- prep: bf16 weights (+q scale fold), biases, rpb+mask table ----------------
// wRM[cls][h][64 qt][64 kt]: rpb + (-100 shift mask) + (-1e30 for kt>=49 pad); 0 for qt>=49.
__global__ void prep_kernel(const float* __restrict__ Wq, const float* __restrict__ Wk,
                            const float* __restrict__ Wv, const float* __restrict__ Wp,
                            const float* __restrict__ bq, const float* __restrict__ bk,
                            const float* __restrict__ bv, const float* __restrict__ bp,
                            const float* __restrict__ tbl,
                            ushort* __restrict__ wW, float* __restrict__ wB,
                            float* __restrict__ wRM) {
  int t = blockIdx.x * 256 + threadIdx.x;
  const float SC = 0.17677669529663687f;  // 32^-0.5
  if (t < 65536) {
    int m = t >> 14, e = t & 16383;
    const float* W = (m == 0) ? Wq : (m == 1) ? Wk : (m == 2) ? Wv : Wp;
    float v = W[e];
    if (m == 0) v *= SC;
    wW[t] = f2bf(v);
  } else if (t < 66048) {
    int t2 = t - 65536;
    int m = t2 >> 7, e = t2 & 127;
    const float* B = (m == 0) ? bq : (m == 1) ? bk : (m == 2) ? bv : bp;
    float v = B[e];
    if (m == 0) v *= SC;
    wB[t2] = v;
  } else if (t < 131584) {
    int t3 = t - 66048;  // [0, 65536)
    int cls = t3 >> 14;
    int r = t3 & 16383;
    int h = r >> 12;
    int rr = r & 4095;
    int qt = rr >> 6, kt = rr & 63;
    float v;
    if (qt >= 49) v = 0.0f;
    else if (kt >= 49) v = -1e30f;
    else {
      int rq = qt / 7, cq = qt % 7, rk = kt / 7, ck = kt % 7;
      v = tbl[((rq - rk + 6) * 13 + (cq - ck + 6)) * 4 + h];
      int eH = (cls >> 1) & 1, eW = cls & 1;
      int ridq = (eH ? (rq < 4 ? 3 : 6) : 0) + (eW ? (cq < 4 ? 1 : 2) : 0);
      int ridk = (eH ? (rk < 4 ? 3 : 6) : 0) + (eW ? (ck < 4 ? 1 : 2) : 0);
      if (ridq != ridk) v -= 100.0f;
    }
    wRM[t3] = v;
  }
}

// LDS layout (ushort units):
//  [0, 9216)      : x_s[49][136] (A/B)  |  p_s[2][64][72] (attn)  |  o_s[49][136] (proj in)
//  [9216, 15880)  : q_s[49][136]
//  [15880, 22544) : k_s[49][136]
//  [22544, 31760) : vT[128][72]   (v transposed: [channel][token])
#define QS 9216
#define KS 15880
#define VT 22544

__global__ __launch_bounds__(512, 4) void swin_kernel(
    const float* __restrict__ X, const ushort* __restrict__ wW,
    const float* __restrict__ wB, const float* __restrict__ wRM,
    float* __restrict__ out) {
  __shared__ ushort lds[31760];
  const int tid = threadIdx.x;
  const int wv = tid >> 6;  // 0..7
  const int lane = tid & 63;
  const int lr = lane & 15;
  const int kg = lane >> 4;

  const int blk = blockIdx.x;
  const int b = blk >> 8;
  const int wid = blk & 255;
  const int wi = wid >> 4, wj = wid & 15;
  const size_t gBase = (size_t)b * (IMG * IMG * 128);

  // ---------------- Phase A: gather rolled window, f32 -> bf16 ----------------
#pragma unroll 1
  for (int idx = tid; idx < 49 * 32; idx += 512) {
    int row = idx >> 5, q4 = idx & 31;
    int r = d7(row), c = row - r * 7;
    int gh = wi * 7 + r + SHF; if (gh >= IMG) gh -= IMG;
    int gw = wj * 7 + c + SHF; if (gw >= IMG) gw -= IMG;
    float4 v = reinterpret_cast<const float4*>(X + gBase + ((size_t)gh * IMG + gw) * 128)[q4];
    ushort4 h4 = { f2bf(v.x), f2bf(v.y), f2bf(v.z), f2bf(v.w) };
    *reinterpret_cast<ushort4*>(&lds[row * 136 + q4 * 4]) = h4;
  }
  __syncthreads();

  const int wc = wv & 3, wt = wv >> 2;
  const int c0 = wc * 32, t0 = wt * 32;
  const int hloc = wv >> 2, mq = wv & 3;  // attn identity (same wave, different roles)
  const int qt = mq * 16 + lr;
  const int qtc = qt > 48 ? 48 : qt;

  // ---------------- Phase B: QKV projections (q,k swapped -> vector writes) ----------------
  {
#pragma unroll 1
    for (int pj = 0; pj < 2; ++pj) {  // q, k: D[co][tok]
      const ushort* W = wW + pj * 16384;
      f32x4 acc[2][2] = {};
#pragma unroll 2
      for (int kk = 0; kk < 4; ++kk) {
        bf16x8 aw[2], bx[2];
#pragma unroll
        for (int mt = 0; mt < 2; ++mt)
          aw[mt] = *reinterpret_cast<const bf16x8*>(&W[(c0 + mt * 16 + lr) * 128 + kk * 32 + kg * 8]);
#pragma unroll
        for (int nt = 0; nt < 2; ++nt) {
          int tok = t0 + nt * 16 + lr; if (tok > 48) tok = 48;
          bx[nt] = *reinterpret_cast<const bf16x8*>(&lds[tok * 136 + kk * 32 + kg * 8]);
        }
#pragma unroll
        for (int mt = 0; mt < 2; ++mt)
#pragma unroll
          for (int nt = 0; nt < 2; ++nt)
            acc[mt][nt] = __builtin_amdgcn_mfma_f32_16x16x32_bf16(aw[mt], bx[nt], acc[mt][nt], 0, 0, 0);
      }
      const int sb = (pj == 0) ? QS : KS;
#pragma unroll
      for (int mt = 0; mt < 2; ++mt) {
        float4 b4 = *reinterpret_cast<const float4*>(&wB[pj * 128 + c0 + mt * 16 + kg * 4]);
#pragma unroll
        for (int nt = 0; nt < 2; ++nt) {
          int tok = t0 + nt * 16 + lr;
          if (tok < 49) {
            ushort4 h4 = { f2bf(acc[mt][nt][0] + b4.x), f2bf(acc[mt][nt][1] + b4.y),
                           f2bf(acc[mt][nt][2] + b4.z), f2bf(acc[mt][nt][3] + b4.w) };
            *reinterpret_cast<ushort4*>(&lds[sb + tok * 136 + c0 + mt * 16 + kg * 4]) = h4;
          }
        }
      }
    }
    {  // v: D[tok][co] -> vT[co][tok] vector writes
      const ushort* W = wW + 2 * 16384;
      f32x4 acc[2][2] = {};
#pragma unroll 2
      for (int kk = 0; kk < 4; ++kk) {
        bf16x8 ax[2], bw[2];
#pragma unroll
        for (int mt = 0; mt < 2; ++mt) {
          int tok = t0 + mt * 16 + lr; if (tok > 48) tok = 48;
          ax[mt] = *reinterpret_cast<const bf16x8*>(&lds[tok * 136 + kk * 32 + kg * 8]);
        }
#pragma unroll
        for (int nt = 0; nt < 2; ++nt)
          bw[nt] = *reinterpret_cast<const bf16x8*>(&W[(c0 + nt * 16 + lr) * 128 + kk * 32 + kg * 8]);
#pragma unroll
        for (int mt = 0; mt < 2; ++mt)
#pragma unroll
          for (int nt = 0; nt < 2; ++nt)
            acc[mt][nt] = __builtin_amdgcn_mfma_f32_16x16x32_bf16(ax[mt], bw[nt], acc[mt][nt], 0, 0, 0);
      }
#pragma unroll
      for (int nt = 0; nt < 2; ++nt) {
        float bias = wB[256 + c0 + nt * 16 + lr];
#pragma unroll
        for (int mt = 0; mt < 2; ++mt) {
          ushort4 h4 = { f2bf(acc[mt][nt][0] + bias), f2bf(acc[mt][nt][1] + bias),
                         f2bf(acc[mt][nt][2] + bias), f2bf(acc[mt][nt][3] + bias) };
          *reinterpret_cast<ushort4*>(&lds[VT + (c0 + nt * 16 + lr) * 72 + t0 + mt * 16 + kg * 4]) = h4;
        }
      }
    }
  }
  __syncthreads();

  // ---------------- Attention: swapped QK^T, lane-local softmax rows ----------------
  const int cls = ((wi == 15) ? 2 : 0) + ((wj == 15) ? 1 : 0);
  f32x4 oacc[2][2] = {};
#pragma unroll
  for (int pass = 0; pass < 2; ++pass) {
    const int h = pass * 2 + hloc;
    // S^T = K Q^T : D[kt][qt]
    f32x4 s[4] = {};
    {
      bf16x8 bq = *reinterpret_cast<const bf16x8*>(&lds[QS + qtc * 136 + h * 32 + kg * 8]);
#pragma unroll
      for (int at = 0; at < 4; ++at) {
        int kt = at * 16 + lr; if (kt > 48) kt = 48;
        bf16x8 ak = *reinterpret_cast<const bf16x8*>(&lds[KS + kt * 136 + h * 32 + kg * 8]);
        s[at] = __builtin_amdgcn_mfma_f32_16x16x32_bf16(ak, bq, s[at], 0, 0, 0);
      }
    }
    // rpb + mask (precomputed) + softmax over kt (16 in-lane + 2 shfl)
    const float* rp = wRM + (((size_t)cls * 4 + h) * 64 + qt) * 64;
    float mx = -3.0e38f;
#pragma unroll
    for (int at = 0; at < 4; ++at) {
      float4 r4 = *reinterpret_cast<const float4*>(&rp[at * 16 + kg * 4]);
      s[at][0] += r4.x; s[at][1] += r4.y; s[at][2] += r4.z; s[at][3] += r4.w;
      mx = fmaxf(mx, fmaxf(fmaxf(s[at][0], s[at][1]), fmaxf(s[at][2], s[at][3])));
    }
    mx = fmaxf(mx, __shfl_xor(mx, 16));
    mx = fmaxf(mx, __shfl_xor(mx, 32));
    float sum = 0.0f;
#pragma unroll
    for (int at = 0; at < 4; ++at) {
#pragma unroll
      for (int i = 0; i < 4; ++i) {
        float e = __expf(s[at][i] - mx);
        s[at][i] = e; sum += e;
      }
    }
    sum += __shfl_xor(sum, 16);
    sum += __shfl_xor(sum, 32);
    float inv = 1.0f / sum;
    const int pb = hloc * 4608 + qt * 72;
#pragma unroll
    for (int at = 0; at < 4; ++at) {
      ushort4 p4 = { f2bf(s[at][0] * inv), f2bf(s[at][1] * inv),
                     f2bf(s[at][2] * inv), f2bf(s[at][3] * inv) };
      *reinterpret_cast<ushort4*>(&lds[pb + at * 16 + kg * 4]) = p4;
    }
    // O^T = V^T P^T : D[d][qt]  (reads only this wave's own P rows: no barrier)
#pragma unroll
    for (int kk = 0; kk < 2; ++kk) {
      bf16x8 bp = *reinterpret_cast<const bf16x8*>(&lds[pb + kk * 32 + kg * 8]);
#pragma unroll
      for (int mt = 0; mt < 2; ++mt) {
        bf16x8 av = *reinterpret_cast<const bf16x8*>(&lds[VT + (h * 32 + mt * 16 + lr) * 72 + kk * 32 + kg * 8]);
        oacc[pass][mt] = __builtin_amdgcn_mfma_f32_16x16x32_bf16(av, bp, oacc[pass][mt], 0, 0, 0);
      }
    }
  }
  __syncthreads();  // all p_s reads done before o_s overwrites R0

  // ---------------- O -> o_s[tok][ch] ----------------
#pragma unroll
  for (int pass = 0; pass < 2; ++pass) {
    const int h = pass * 2 + hloc;
#pragma unroll
    for (int mt = 0; mt < 2; ++mt) {
      if (qt < 49) {
        ushort4 h4 = { f2bf(oacc[pass][mt][0]), f2bf(oacc[pass][mt][1]),
                       f2bf(oacc[pass][mt][2]), f2bf(oacc[pass][mt][3]) };
        *reinterpret_cast<ushort4*>(&lds[qt * 136 + h * 32 + mt * 16 + kg * 4]) = h4;
      }
    }
  }
  __syncthreads();

  // ---------------- Phase E: output projection (swapped) + float4 scatter ----------------
  {
    const ushort* W = wW + 3 * 16384;
    f32x4 acc[2][2] = {};
#pragma unroll 2
    for (int kk = 0; kk < 4; ++kk) {
      bf16x8 aw[2], bo[2];
#pragma unroll
      for (int mt = 0; mt < 2; ++mt)
        aw[mt] = *reinterpret_cast<const bf16x8*>(&W[(c0 + mt * 16 + lr) * 128 + kk * 32 + kg * 8]);
#pragma unroll
      for (int nt = 0; nt < 2; ++nt) {
        int tok = t0 + nt * 16 + lr; if (tok > 48) tok = 48;
        bo[nt] = *reinterpret_cast<const bf16x8*>(&lds[tok * 136 + kk * 32 + kg * 8]);
      }
#pragma unroll
      for (int mt = 0; mt < 2; ++mt)
#pragma unroll
        for (int nt = 0; nt < 2; ++nt)
          acc[mt][nt] = __builtin_amdgcn_mfma_f32_16x16x32_bf16(aw[mt], bo[nt], acc[mt][nt], 0, 0, 0);
    }
#pragma unroll
    for (int mt = 0; mt < 2; ++mt) {
      float4 b4 = *reinterpret_cast<const float4*>(&wB[384 + c0 + mt * 16 + kg * 4]);
#pragma unroll
      for (int nt = 0; nt < 2; ++nt) {
        int tok = t0 + nt * 16 + lr;
        if (tok < 49) {
          int r = d7(tok), c = tok - r * 7;
          int gh = wi * 7 + r + SHF; if (gh >= IMG) gh -= IMG;
          int gw = wj * 7 + c + SHF; if (gw >= IMG) gw -= IMG;
          float4 o4 = { acc[mt][nt][0] + b4.x, acc[mt][nt][1] + b4.y,
                        acc[mt][nt][2] + b4.z, acc[mt][nt][3] + b4.w };
          *reinterpret_cast<float4*>(out + gBase + ((size_t)gh * IMG + gw) * 128 + c0 + mt * 16 + kg * 4) = o4;
        }
      }
    }
  }
}

extern "C" void kernel_launch(void* const* d_in, const int* in_sizes, int n_in,
                              void* d_out, int out_size, void* d_ws, size_t ws_size,
                              hipStream_t stream) {
  const float* X = (const float*)d_in[0];
  const float* Wq = (const float*)d_in[3];
  const float* Wk = (const float*)d_in[4];
  const float* Wv = (const float*)d_in[5];
  const float* Wp = (const float*)d_in[6];
  const float* bq = (const float*)d_in[7];
  const float* bk = (const float*)d_in[8];
  const float* bv = (const float*)d_in[9];
  const float* bp = (const float*)d_in[10];
  const float* tbl = (const float*)d_in[11];

  ushort* wW = (ushort*)d_ws;                             // 4 x [128][128] bf16 = 131072 B
  float* wB = (float*)((char*)d_ws + 131072);             // 4 x [128] f32   = 2048 B
  float* wRM = (float*)((char*)d_ws + 131072 + 2048);     // [4][4][64][64] f32 = 262144 B

  prep_kernel<<<dim3(514), dim3(256), 0, stream>>>(Wq, Wk, Wv, Wp, bq, bk, bv, bp, tbl, wW, wB, wRM);
  swin_kernel<<<dim3(8192), dim3(512), 0, stream>>>(X, wW, wB, wRM, (float*)d_out);
}